// Round 1
// baseline (319.865 us; speedup 1.0000x reference)
//
#include <hip/hip_runtime.h>
#include <stdint.h>

// ---------------------------------------------------------------------------
// MS_SSA_Conv: spiking self-attention block.
// T=4 B=8 C=384 N=1024(HW) heads=8 hd=48. TAU=2, VTH=0.5, EPS=1e-5.
// Key ideas:
//  * all conv inputs are binary spikes -> exact in bf16; fp32 weights split
//    into 3 bf16 parts for QKV convs (spike decisions need fp32-grade eps),
//    1 part for proj conv (output tolerance is ~0.1).
//  * kv reduction = exact integer counts (sum of {0,1} products) -> atomicAdd
//    in fp32 is exact & order-independent.
//  * GEMMs: mfma_f32_16x16x32_bf16, 64x64 block tile, BK=64,
//    global_load_lds(16B) staging with XOR-8 chunk swizzle so ds_read_b128
//    fragment reads are conflict-free.
//  * spikes stored [T,B,N,C] bf16 (c fastest) = B^T layout for MFMA B-frags.
// ---------------------------------------------------------------------------

typedef unsigned short u16;
typedef __attribute__((ext_vector_type(8))) short bf16x8;
typedef __attribute__((ext_vector_type(4))) float f32x4;

#define AS1 __attribute__((address_space(1)))
#define AS3 __attribute__((address_space(3)))

__device__ __forceinline__ void async16(const void* g, void* l) {
    __builtin_amdgcn_global_load_lds((const AS1 unsigned int*)g,
                                     (AS3 unsigned int*)l, 16, 0, 0);
}

__device__ __forceinline__ f32x4 mfma16(bf16x8 a, bf16x8 b, f32x4 c) {
    return __builtin_amdgcn_mfma_f32_16x16x32_bf16(a, b, c, 0, 0, 0);
}

__device__ __forceinline__ u16 f2bf(float f) {  // RNE fp32->bf16
    uint32_t x = __float_as_uint(f);
    return (u16)((x + 0x7FFFu + ((x >> 16) & 1u)) >> 16);
}
__device__ __forceinline__ float bf2f(u16 h) {
    return __uint_as_float(((uint32_t)h) << 16);
}

#define SPIKE1 ((u16)0x3F80)  // bf16 1.0

// ---------------------------------------------------------------------------
// K0: build weight matrices.
//  Asplit [1152][1152] bf16: rows = {q,k,v} stacked (o in 0..383 each);
//    cols = 3 parts * 384 c (part-major). w ~= p0+p1+p2, residual ~2^-27.
//  Aproj  [384][384] bf16: single-part proj weights.
// ---------------------------------------------------------------------------
__global__ void prep_kernel(const float* __restrict__ qw, const float* __restrict__ kw,
                            const float* __restrict__ vw, const float* __restrict__ pw,
                            u16* __restrict__ Asplit, u16* __restrict__ Aproj) {
    int id = blockIdx.x * 256 + threadIdx.x;
    if (id >= 1152 * 384) return;
    int m = id / 384, c = id % 384;
    int br = m / 384, o = m % 384;
    const float* W = (br == 0) ? qw : (br == 1) ? kw : vw;
    float w = W[o * 384 + c];
    u16 h0 = f2bf(w);
    float r1 = w - bf2f(h0);
    u16 h1 = f2bf(r1);
    float r2 = r1 - bf2f(h1);
    u16 h2 = f2bf(r2);
    u16* row = Asplit + (size_t)m * 1152;
    row[c] = h0; row[384 + c] = h1; row[768 + c] = h2;
    if (br == 0) Aproj[o * 384 + c] = f2bf(pw[o * 384 + c]);
}

// ---------------------------------------------------------------------------
// K1: shortcut LIF on x, store spikes transposed: xs[t,b,n,c] bf16.
// Exact numpy op order: v = v + (x - v)/2 ; s = (v >= 0.5) ; v *= (1-s).
// grid (ntile=16, ctile=6, b=8), 256 thr. 64x64 (c,n) tile, LDS transpose.
// ---------------------------------------------------------------------------
__global__ __launch_bounds__(256) void lifx_kernel(const float* __restrict__ x,
                                                   u16* __restrict__ xs) {
    __shared__ u16 Tr[64 * 72];
    int b = blockIdx.z, c0 = blockIdx.y * 64, n0 = blockIdx.x * 64;
    int tid = threadIdx.x;
    int nj = (tid & 15) * 4;   // n within tile (float4)
    int ci = tid >> 4;         // c row group (16 rows/pass)
    float v[4][4];
#pragma unroll
    for (int p = 0; p < 4; p++)
#pragma unroll
        for (int e = 0; e < 4; e++) v[p][e] = 0.0f;

    for (int t = 0; t < 4; t++) {
#pragma unroll
        for (int p = 0; p < 4; p++) {
            const float* src = x + ((size_t)((t * 8 + b) * 384 + c0 + p * 16 + ci)) * 1024 + n0 + nj;
            float4 xv = *(const float4*)src;
            float xa[4] = {xv.x, xv.y, xv.z, xv.w};
#pragma unroll
            for (int e = 0; e < 4; e++) {
                float vv = v[p][e];
                vv = __fadd_rn(vv, __fmul_rn(__fsub_rn(xa[e], vv), 0.5f));
                bool sp = (vv >= 0.5f);
                v[p][e] = sp ? 0.0f : vv;
                Tr[(nj + e) * 72 + p * 16 + ci] = sp ? SPIKE1 : (u16)0;
            }
        }
        __syncthreads();
#pragma unroll
        for (int p = 0; p < 4; p++) {
            int nr = p * 16 + (tid >> 4);
            int c4 = (tid & 15) * 4;
            *(ushort4*)(xs + ((size_t)((t * 8 + b) * 1024 + n0 + nr)) * 384 + c0 + c4) =
                *(const ushort4*)&Tr[nr * 72 + c4];
        }
        __syncthreads();
    }
}

// ---------------------------------------------------------------------------
// GEMM staging helper geometry (shared by K2/K5):
//  tile = 64 rows x 64 k bf16 = 8KB = 512 chunks of 16B. chunk slot l holds
//  global chunk ( row=l>>3 , (l&7)^(row&7) )  [XOR swizzle].
//  Fragment read for global chunk g of row r lives at slot g^(r&7).
// ---------------------------------------------------------------------------

// K2: QKV conv (3-part split K=1152) + BN + LIF over t. One block owns a
// 64x64 (channel,pixel) tile of ONE branch for ONE b, loops t keeping the
// LIF membrane in registers. Spikes written to {q,k,v}s[t,b,n,c] bf16.
// grid (ntile=16, mtile=18, b=8), 256 thr (4 waves, 2x2 of 32x32).
__global__ __launch_bounds__(256) void qkv_kernel(
    const u16* __restrict__ Asplit, const u16* __restrict__ xs,
    u16* __restrict__ qs, u16* __restrict__ ks, u16* __restrict__ vs,
    const float* __restrict__ qg, const float* __restrict__ qb, const float* __restrict__ qm, const float* __restrict__ qv,
    const float* __restrict__ kg, const float* __restrict__ kb, const float* __restrict__ km, const float* __restrict__ kvr,
    const float* __restrict__ vg, const float* __restrict__ vb, const float* __restrict__ vm, const float* __restrict__ vvr) {
    __shared__ __align__(16) u16 smem[8192];  // A:[0,4096) B:[4096,8192); Tr reuses [0,4608)
    u16* At = smem;
    u16* Bt = smem + 4096;

    int b = blockIdx.z, mt = blockIdx.y, nt = blockIdx.x;
    int m0 = mt * 64, n0 = nt * 64;
    int branch = mt / 6;
    int o0 = (mt % 6) * 64;
    int tid = threadIdx.x, wave = tid >> 6, lane = tid & 63;
    int l15 = lane & 15, quad = lane >> 4;
    int wm = (wave & 1) * 32, wn = (wave >> 1) * 32;

    const float* g_ = (branch == 0) ? qg : (branch == 1) ? kg : vg;
    const float* b_ = (branch == 0) ? qb : (branch == 1) ? kb : vb;
    const float* m_ = (branch == 0) ? qm : (branch == 1) ? km : vm;
    const float* v_ = (branch == 0) ? qv : (branch == 1) ? kvr : vvr;
    u16* dstp = (branch == 0) ? qs : (branch == 1) ? ks : vs;

    // per-row BN params (rows owned by this lane: wm + i*16 + quad*4 + e)
    float scB[2][4], mB[2][4], btB[2][4];
#pragma unroll
    for (int i = 0; i < 2; i++)
#pragma unroll
        for (int e = 0; e < 4; e++) {
            int o = o0 + wm + i * 16 + quad * 4 + e;
            scB[i][e] = g_[o] / sqrtf(v_[o] + 1e-5f);
            mB[i][e] = m_[o];
            btB[i][e] = b_[o];
        }

    float vmem[2][2][4];
#pragma unroll
    for (int i = 0; i < 2; i++)
#pragma unroll
        for (int j = 0; j < 2; j++)
#pragma unroll
            for (int e = 0; e < 4; e++) vmem[i][j][e] = 0.0f;

    for (int t = 0; t < 4; t++) {
        f32x4 acc[2][2];
#pragma unroll
        for (int i = 0; i < 2; i++)
#pragma unroll
            for (int j = 0; j < 2; j++) acc[i][j] = (f32x4){0.f, 0.f, 0.f, 0.f};

        const u16* Bsrc = xs + ((size_t)((t * 8 + b) * 1024 + n0)) * 384;

        for (int kkb = 0; kkb < 18; kkb++) {
            int kk = kkb * 64;
            int ck = kk - ((kk >= 768) ? 768 : (kk >= 384) ? 384 : 0);  // kk % 384
            __syncthreads();  // previous stage's LDS reads done
#pragma unroll
            for (int ii = 0; ii < 2; ii++) {
                int lbase = wave * 128 + ii * 64;
                int l = lbase + lane;
                int row = l >> 3;
                int cs = (l & 7) ^ (row & 7);
                async16(Asplit + (size_t)(m0 + row) * 1152 + kk + cs * 8, &At[lbase * 8]);
                async16(Bsrc + (size_t)row * 384 + ck + cs * 8, &Bt[lbase * 8]);
            }
            __syncthreads();  // drains vmcnt -> staged data visible
#pragma unroll
            for (int h = 0; h < 2; h++) {
                bf16x8 af[2], bfr[2];
#pragma unroll
                for (int i = 0; i < 2; i++) {
                    int row = wm + i * 16 + l15;
                    int ch = (h * 4 + quad) ^ (row & 7);
                    af[i] = *(const bf16x8*)&At[row * 64 + ch * 8];
                }
#pragma unroll
                for (int j = 0; j < 2; j++) {
                    int nr = wn + j * 16 + l15;
                    int ch = (h * 4 + quad) ^ (nr & 7);
                    bfr[j] = *(const bf16x8*)&Bt[nr * 64 + ch * 8];
                }
#pragma unroll
                for (int i = 0; i < 2; i++)
#pragma unroll
                    for (int j = 0; j < 2; j++) acc[i][j] = mfma16(af[i], bfr[j], acc[i][j]);
            }
        }

        // epilogue: BN (+numpy op order) + LIF + spike -> LDS [n][m] -> global
        __syncthreads();
        u16* Tr = smem;
#pragma unroll
        for (int i = 0; i < 2; i++) {
            int mb = wm + i * 16 + quad * 4;
#pragma unroll
            for (int j = 0; j < 2; j++) {
                int nr = wn + j * 16 + l15;
                u16 sv[4];
#pragma unroll
                for (int e = 0; e < 4; e++) {
                    float a = acc[i][j][e];
                    a = __fadd_rn(__fmul_rn(__fsub_rn(a, mB[i][e]), scB[i][e]), btB[i][e]);
                    float vv = vmem[i][j][e];
                    vv = __fadd_rn(vv, __fmul_rn(__fsub_rn(a, vv), 0.5f));
                    bool sp = (vv >= 0.5f);
                    vmem[i][j][e] = sp ? 0.0f : vv;
                    sv[e] = sp ? SPIKE1 : (u16)0;
                }
                ushort4 s4; s4.x = sv[0]; s4.y = sv[1]; s4.z = sv[2]; s4.w = sv[3];
                *(ushort4*)&Tr[nr * 72 + mb] = s4;
            }
        }
        __syncthreads();
        int rbase = (t * 8 + b) * 1024 + n0;
#pragma unroll
        for (int p = 0; p < 4; p++) {
            int nr = p * 16 + (tid >> 4);
            int c4 = (tid & 15) * 4;
            *(ushort4*)(dstp + (size_t)(rbase + nr) * 384 + o0 + c4) = *(const ushort4*)&Tr[nr * 72 + c4];
        }
        // next t's first __syncthreads protects Tr from restaging
    }
}

// ---------------------------------------------------------------------------
// K3: kv[t,b,c] = sum_n k_s*v_s  (exact integer counts; atomicAdd fp32 exact)
// grid (nchunk=16, tb=32), 384 thr (thread = channel c).
// ---------------------------------------------------------------------------
__global__ void kvred_kernel(const u16* __restrict__ ks, const u16* __restrict__ vs,
                             float* __restrict__ r) {
    int tb = blockIdx.y, nc = blockIdx.x, c = threadIdx.x;
    const u16* kp = ks + ((size_t)(tb * 1024 + nc * 64)) * 384 + c;
    const u16* vp = vs + ((size_t)(tb * 1024 + nc * 64)) * 384 + c;
    float cnt = 0.0f;
#pragma unroll 4
    for (int nn = 0; nn < 64; nn++) {
        u16 a = kp[(size_t)nn * 384];
        u16 bb = vp[(size_t)nn * 384];
        if ((a & bb) == SPIKE1) cnt += 1.0f;
    }
    atomicAdd(&r[tb * 384 + c], cnt);
}

// K4: talking heads (8x8 fp32) + LIF over t -> kvs[t,b,c] bf16 {0,1}
__global__ void talking_kernel(const float* __restrict__ r, const float* __restrict__ th,
                               u16* __restrict__ kvs) {
    int id = blockIdx.x * 256 + threadIdx.x;
    if (id >= 8 * 384) return;
    int b = id / 384, c = id % 384;
    int oh = c / 48, d = c % 48;
    float v = 0.0f;
    for (int t = 0; t < 4; t++) {
        const float* rr = r + (t * 8 + b) * 384 + d;
        float s = 0.0f;
#pragma unroll
        for (int h = 0; h < 8; h++) s = __fmaf_rn(th[oh * 8 + h], rr[h * 48], s);
        v = __fadd_rn(v, __fmul_rn(__fsub_rn(s, v), 0.5f));
        bool sp = (v >= 0.5f);
        v = sp ? 0.0f : v;
        kvs[(t * 8 + b) * 384 + c] = sp ? SPIKE1 : (u16)0;
    }
}

// K4b: gate q spikes in place: qs[t,b,n,c] &= kvs[t,b,c]
__global__ void gate_kernel(u16* __restrict__ qs, const u16* __restrict__ kvs) {
    int gidx = blockIdx.x * 256 + threadIdx.x;  // 32*1024*96 ushort4 chunks
    int c4 = gidx % 96;
    int row = gidx / 96;
    int tb = row >> 10;
    ushort4 q = *(ushort4*)(qs + (size_t)gidx * 4);
    ushort4 kv = *(const ushort4*)(kvs + tb * 384 + c4 * 4);
    q.x = (kv.x == SPIKE1) ? q.x : (u16)0;
    q.y = (kv.y == SPIKE1) ? q.y : (u16)0;
    q.z = (kv.z == SPIKE1) ? q.z : (u16)0;
    q.w = (kv.w == SPIKE1) ? q.w : (u16)0;
    *(ushort4*)(qs + (size_t)gidx * 4) = q;
}

// ---------------------------------------------------------------------------
// K5: proj conv (K=384, 1-part bf16) + bias + BN + residual -> out fp32.
// grid (ntile=16, mtile=6, tb=32), 256 thr. Same GEMM core as K2.
// ---------------------------------------------------------------------------
__global__ __launch_bounds__(256) void proj_kernel(
    const u16* __restrict__ Aproj, const u16* __restrict__ qs, const float* __restrict__ xin,
    const float* __restrict__ pb, const float* __restrict__ pg, const float* __restrict__ pbe,
    const float* __restrict__ pm, const float* __restrict__ pv, float* __restrict__ out) {
    __shared__ __align__(16) u16 smem[8192];
    u16* At = smem;
    u16* Bt = smem + 4096;

    int tb = blockIdx.z, mt = blockIdx.y, nt = blockIdx.x;
    int m0 = mt * 64, n0 = nt * 64;
    int tid = threadIdx.x, wave = tid >> 6, lane = tid & 63;
    int l15 = lane & 15, quad = lane >> 4;
    int wm = (wave & 1) * 32, wn = (wave >> 1) * 32;

    f32x4 acc[2][2];
#pragma unroll
    for (int i = 0; i < 2; i++)
#pragma unroll
        for (int j = 0; j < 2; j++) acc[i][j] = (f32x4){0.f, 0.f, 0.f, 0.f};

    const u16* Bsrc = qs + ((size_t)(tb * 1024 + n0)) * 384;

    for (int kkb = 0; kkb < 6; kkb++) {
        int kk = kkb * 64;
        __syncthreads();
#pragma unroll
        for (int ii = 0; ii < 2; ii++) {
            int lbase = wave * 128 + ii * 64;
            int l = lbase + lane;
            int row = l >> 3;
            int cs = (l & 7) ^ (row & 7);
            async16(Aproj + (size_t)(m0 + row) * 384 + kk + cs * 8, &At[lbase * 8]);
            async16(Bsrc + (size_t)row * 384 + kk + cs * 8, &Bt[lbase * 8]);
        }
        __syncthreads();
#pragma unroll
        for (int h = 0; h < 2; h++) {
            bf16x8 af[2], bfr[2];
#pragma unroll
            for (int i = 0; i < 2; i++) {
                int row = wm + i * 16 + l15;
                int ch = (h * 4 + quad) ^ (row & 7);
                af[i] = *(const bf16x8*)&At[row * 64 + ch * 8];
            }
#pragma unroll
            for (int j = 0; j < 2; j++) {
                int nr = wn + j * 16 + l15;
                int ch = (h * 4 + quad) ^ (nr & 7);
                bfr[j] = *(const bf16x8*)&Bt[nr * 64 + ch * 8];
            }
#pragma unroll
            for (int i = 0; i < 2; i++)
#pragma unroll
                for (int j = 0; j < 2; j++) acc[i][j] = mfma16(af[i], bfr[j], acc[i][j]);
        }
    }

    // epilogue: y = conv + b; (y-mean)*scale + beta; + identity. numpy op order.
#pragma unroll
    for (int i = 0; i < 2; i++) {
#pragma unroll
        for (int e = 0; e < 4; e++) {
            int o = m0 + wm + i * 16 + quad * 4 + e;
            float scale = pg[o] / sqrtf(pv[o] + 1e-5f);
            float mean = pm[o], beta = pbe[o], bias = pb[o];
#pragma unroll
            for (int j = 0; j < 2; j++) {
                int n = n0 + wn + j * 16 + l15;
                size_t idx = ((size_t)tb * 384 + o) * 1024 + n;
                float y = __fadd_rn(acc[i][j][e], bias);
                y = __fadd_rn(__fmul_rn(__fsub_rn(y, mean), scale), beta);
                out[idx] = __fadd_rn(y, xin[idx]);
            }
        }
    }
}

// ---------------------------------------------------------------------------
extern "C" void kernel_launch(void* const* d_in, const int* in_sizes, int n_in,
                              void* d_out, int out_size, void* d_ws, size_t ws_size,
                              hipStream_t stream) {
    (void)in_sizes; (void)n_in; (void)out_size; (void)ws_size;
    const float* x  = (const float*)d_in[0];
    const float* qw = (const float*)d_in[1];
    const float* kw = (const float*)d_in[2];
    const float* vw = (const float*)d_in[3];
    const float* th = (const float*)d_in[4];
    const float* pw = (const float*)d_in[5];
    const float* pb = (const float*)d_in[6];
    const float* qg = (const float*)d_in[7],  *qbe = (const float*)d_in[8];
    const float* qm = (const float*)d_in[9],  *qv  = (const float*)d_in[10];
    const float* kg = (const float*)d_in[11], *kbe = (const float*)d_in[12];
    const float* km = (const float*)d_in[13], *kv_ = (const float*)d_in[14];
    const float* vg = (const float*)d_in[15], *vbe = (const float*)d_in[16];
    const float* vm = (const float*)d_in[17], *vv_ = (const float*)d_in[18];
    const float* pg = (const float*)d_in[19], *pbe = (const float*)d_in[20];
    const float* pm = (const float*)d_in[21], *pv  = (const float*)d_in[22];
    float* out = (float*)d_out;

    char* w = (char*)d_ws;
    const size_t SPIKES = (size_t)32 * 1024 * 384 * 2;  // 25,165,824 B each
    u16* xs     = (u16*)(w);
    u16* qs     = (u16*)(w + SPIKES);
    u16* ks     = (u16*)(w + 2 * SPIKES);
    u16* vs     = (u16*)(w + 3 * SPIKES);
    u16* Asplit = (u16*)(w + 4 * SPIKES);                       // 2,654,208 B
    u16* Aproj  = (u16*)(w + 4 * SPIKES + 2654208);             //   294,912 B
    float* r    = (float*)(w + 4 * SPIKES + 2654208 + 294912);  //    49,152 B
    u16* kvs    = (u16*)(w + 4 * SPIKES + 2654208 + 294912 + 49152);  // 24,576 B

    hipMemsetAsync(r, 0, 32 * 384 * sizeof(float), stream);

    prep_kernel<<<1728, 256, 0, stream>>>(qw, kw, vw, pw, Asplit, Aproj);
    lifx_kernel<<<dim3(16, 6, 8), 256, 0, stream>>>(x, xs);
    qkv_kernel<<<dim3(16, 18, 8), 256, 0, stream>>>(Asplit, xs, qs, ks, vs,
                                                    qg, qbe, qm, qv,
                                                    kg, kbe, km, kv_,
                                                    vg, vbe, vm, vv_);
    kvred_kernel<<<dim3(16, 32), 384, 0, stream>>>(ks, vs, r);
    talking_kernel<<<12, 256, 0, stream>>>(r, th, kvs);
    gate_kernel<<<12288, 256, 0, stream>>>(qs, kvs);
    proj_kernel<<<dim3(16, 6, 32), 256, 0, stream>>>(Aproj, qs, x, pb, pg, pbe, pm, pv, out);
}